// Round 5
// baseline (221.899 us; speedup 1.0000x reference)
//
#include <hip/hip_runtime.h>

// B=4, T=4096, C=512, H=64 causal attention head, scale=C^-0.5, fp32 I/O.
// R5: S^T=K*Q^T trick (P packs to LDS with v_perm b64 writes, b128 readback),
// complementary long/short block pairing, bf16 merge buffer (4 blocks/CU),
// proj split into 512 blocks of 256 threads.

typedef __attribute__((ext_vector_type(8))) __bf16 bf16x8;
typedef __attribute__((ext_vector_type(8))) unsigned short u16x8;
typedef __attribute__((ext_vector_type(4))) float f32x4;

#define B_ 4
#define T_ 4096
#define C_ 512
#define H_ 64
#define BT (B_ * T_)

#define QSCALE (0.04419417382415922f * 1.4426950408889634f)  // C^-0.5 * log2(e)

__device__ __forceinline__ unsigned short f2bf(float f) {
    unsigned int u = __builtin_bit_cast(unsigned int, f);
    u += 0x7fffu + ((u >> 16) & 1u);
    return (unsigned short)(u >> 16);
}

// pack hi16(a),hi16(b) -> u32 {bf16(b), bf16(a)<<16}  (truncation)
__device__ __forceinline__ unsigned int pkbf(float hi, float lo) {
    return __builtin_amdgcn_perm(__builtin_bit_cast(unsigned int, hi),
                                 __builtin_bit_cast(unsigned int, lo), 0x07060302u);
}

__device__ __forceinline__ f32x4 mfma16(bf16x8 a, bf16x8 b, f32x4 c) {
    return __builtin_amdgcn_mfma_f32_16x16x32_bf16(a, b, c, 0, 0, 0);
}

// ---------------------------------------------------------------------------
// Kernel 0: Wt packed in MFMA B-fragment order.
// ---------------------------------------------------------------------------
__global__ __launch_bounds__(256) void wt_kernel(const float* __restrict__ Wk,
                                                 const float* __restrict__ Wq,
                                                 const float* __restrict__ Wv,
                                                 unsigned short* __restrict__ Wtp) {
    int gid = blockIdx.x * 256 + threadIdx.x;  // 3*64*512
    int fidx = gid >> 9;
    int li = gid & 511;
    int lane = li >> 3, j = li & 7;
    int m3 = fidx / 64;
    int rem = fidx & 63;
    int nt = rem >> 4, kc = rem & 15;
    int h = nt * 16 + (lane & 15);
    int c = kc * 32 + (lane >> 4) * 8 + j;
    const float* W = (m3 == 0) ? Wk : ((m3 == 1) ? Wq : Wv);
    Wtp[gid] = f2bf(W[c * H_ + h]);
}

// ---------------------------------------------------------------------------
// Kernel 1: projections. 32 rows/block, 256 thr = 2 strips x 2 kc-halves.
// ---------------------------------------------------------------------------
__global__ __launch_bounds__(256, 4) void proj_kernel(const float* __restrict__ x,
                                                      const unsigned short* __restrict__ Wtp,
                                                      unsigned short* __restrict__ Kf,
                                                      unsigned short* __restrict__ Qf,
                                                      unsigned short* __restrict__ Vf) {
    __shared__ __align__(16) char smem[2 * 64 * 52 * 4];   // 26624 B
    float* Mg = (float*)smem;                               // [2][64][52] f32
    unsigned short* Ks_l = (unsigned short*)smem;           // [32][68]
    unsigned short* Qs_l = Ks_l + 32 * 68;
    unsigned short* Vt_l = Qs_l + 32 * 68;                  // [64 h][34]

    const int tid = threadIdx.x;
    const int t0 = blockIdx.x * 32;
    const int wave = tid >> 6;
    const int ws = wave & 1;       // strip
    const int wh = wave >> 1;      // kc half
    const int lane = tid & 63;
    const int lane15 = lane & 15;
    const int quad = lane >> 4;

    f32x4 acc[12];
#pragma unroll
    for (int i = 0; i < 12; ++i) acc[i] = (f32x4){0.f, 0.f, 0.f, 0.f};

    const float* xrow = x + (long)(t0 + ws * 16 + lane15) * C_;

#pragma unroll
    for (int kk = 0; kk < 8; ++kk) {
        const int kc = wh * 8 + kk;
        const float4 a0 = *(const float4*)(xrow + kc * 32 + quad * 8);
        const float4 a1 = *(const float4*)(xrow + kc * 32 + quad * 8 + 4);
        u16x8 t;
        t[0] = f2bf(a0.x); t[1] = f2bf(a0.y); t[2] = f2bf(a0.z); t[3] = f2bf(a0.w);
        t[4] = f2bf(a1.x); t[5] = f2bf(a1.y); t[6] = f2bf(a1.z); t[7] = f2bf(a1.w);
        bf16x8 a = __builtin_bit_cast(bf16x8, t);
#pragma unroll
        for (int m3 = 0; m3 < 3; ++m3) {
#pragma unroll
            for (int nt = 0; nt < 4; ++nt) {
                const bf16x8 b = *(const bf16x8*)&Wtp[(((m3 * 4 + nt) * 16 + kc) << 9) + lane * 8];
                acc[m3 * 4 + nt] = mfma16(a, b, acc[m3 * 4 + nt]);
            }
        }
    }

    // kc merge through LDS
    if (wh == 1) {
        float* mg = Mg + (ws * 64 + lane) * 52;
#pragma unroll
        for (int i = 0; i < 12; ++i) *(f32x4*)(mg + i * 4) = acc[i];
    }
    __syncthreads();
    if (wh == 0) {
        const float* mg = Mg + (ws * 64 + lane) * 52;
#pragma unroll
        for (int i = 0; i < 12; ++i) acc[i] += *(const f32x4*)(mg + i * 4);
    }
    __syncthreads();  // Mg dead

    if (wh == 0) {
#pragma unroll
        for (int nt = 0; nt < 4; ++nt) {
            int col = nt * 16 + lane15;
#pragma unroll
            for (int r = 0; r < 4; ++r) {
                int row_l = ws * 16 + quad * 4 + r;
                Ks_l[row_l * 68 + col] = f2bf(acc[0 * 4 + nt][r]);
                Qs_l[row_l * 68 + col] = f2bf(acc[1 * 4 + nt][r] * QSCALE);
                Vt_l[col * 34 + row_l] = f2bf(acc[2 * 4 + nt][r]);
            }
        }
    }
    __syncthreads();

    // Packed writes: 12 frags, 3 per wave.
    const int b = t0 >> 12;
    const int tloc = t0 & 4095;
    const int st = wave >> 1, kk = wave & 1;
    const long gs = (long)(b * 256 + (tloc >> 4) + st);
    bf16x8 kv = *(const bf16x8*)&Ks_l[(st * 16 + lane15) * 68 + kk * 32 + quad * 8];
    *(bf16x8*)&Kf[(gs * 2 + kk) * 512 + lane * 8] = kv;
    bf16x8 qv = *(const bf16x8*)&Qs_l[(st * 16 + lane15) * 68 + kk * 32 + quad * 8];
    *(bf16x8*)&Qf[(gs * 2 + kk) * 512 + lane * 8] = qv;
    // Vf: block covers s_local64 = (tloc&32) + [0,32); frag f = hf*2 + vkk
    const int hf = wave;                      // 0..3
    const int vkk = (tloc >> 5) & 1;
    bf16x8 vv = *(const bf16x8*)&Vt_l[(hf * 16 + lane15) * 34 + quad * 8];
    const long sb = (long)(b * 64 + (tloc >> 6));
    *(bf16x8*)&Vf[(sb * 8 + hf * 2 + vkk) * 512 + lane * 8] = vv;
}

// ---------------------------------------------------------------------------
// Kernel 2: attention. Block = (b, 32-row strip), 8-way K-split waves.
// S^T = K*Q^T so P regs are s-contiguous -> perm-pack + ds_write_b64.
// ---------------------------------------------------------------------------
#define PSP 72
#define SMEM_A (8 * 32 * PSP * 2 + 8 * 32 * 4)

__global__ __launch_bounds__(512, 8) void attn_kernel(const unsigned short* __restrict__ Qf,
                                                      const unsigned short* __restrict__ Kf,
                                                      const unsigned short* __restrict__ Vf,
                                                      float* __restrict__ out) {
    __shared__ __align__(16) char smem[SMEM_A];
    unsigned short* Ps = (unsigned short*)smem;          // loop phase (per-wave)
    unsigned short* Ob = (unsigned short*)smem;          // merge phase, bf16 pitch 68
    float* Ll = (float*)(smem + 8 * 32 * PSP * 2);

    const int tid = threadIdx.x;
    const int wave = tid >> 6;
    const int lane = tid & 63;
    const int lane15 = lane & 15;
    const int quad = lane >> 4;
    const int b = blockIdx.y;
    // complementary pairing: y<2 descending, y>=2 ascending
    const int strip32 = (blockIdx.y < 2) ? (127 - blockIdx.x) : blockIdx.x;
    const int r0 = strip32 * 32;

    // Q as B-operand fragments (B layout == stored frag layout)
    const unsigned short* qb = Qf + ((long)(b * 256 + strip32 * 2) * 2) * 512 + lane * 8;
    bf16x8 qf[2][2];
    qf[0][0] = *(const bf16x8*)qb;
    qf[0][1] = *(const bf16x8*)(qb + 512);
    qf[1][0] = *(const bf16x8*)(qb + 1024);
    qf[1][1] = *(const bf16x8*)(qb + 1536);

    f32x4 o_acc[2][4];
    float l_acc[2] = {0.f, 0.f};
#pragma unroll
    for (int qh = 0; qh < 2; ++qh)
#pragma unroll
        for (int hf = 0; hf < 4; ++hf) o_acc[qh][hf] = (f32x4){0.f, 0.f, 0.f, 0.f};

    const int ntiles = (r0 + 95) >> 6;
    unsigned short* pw = Ps + wave * 32 * PSP;

    for (int kc = wave; kc < ntiles; kc += 8) {
        const int s0 = kc * 64;
        const unsigned short* kb = Kf + ((long)(b * 256 + (s0 >> 4)) * 2) * 512 + lane * 8;
        const unsigned short* vb = Vf + ((long)(b * 64 + (s0 >> 6)) * 8) * 512 + lane * 8;

        // S^T = K Q^T : element (s = s0+ct*16+quad*4+r, q = r0+qh*16+lane15)
        f32x4 st[2][4];
#pragma unroll
        for (int ct = 0; ct < 4; ++ct) {
            bf16x8 k0 = *(const bf16x8*)(kb + ct * 1024);
            bf16x8 k1 = *(const bf16x8*)(kb + ct * 1024 + 512);
#pragma unroll
            for (int qh = 0; qh < 2; ++qh) {
                f32x4 z = (f32x4){0.f, 0.f, 0.f, 0.f};
                z = mfma16(k0, qf[qh][0], z);
                z = mfma16(k1, qf[qh][1], z);
                st[qh][ct] = z;
            }
        }

        // V^T fragments (overlap with softmax)
        bf16x8 vf[8];
#pragma unroll
        for (int f = 0; f < 8; ++f) vf[f] = *(const bf16x8*)(vb + f * 512);

        // causal mask on straddle tiles
        if (s0 + 63 > r0) {
#pragma unroll
            for (int ct = 0; ct < 4; ++ct) {
                int sbase = s0 + ct * 16 + quad * 4;
#pragma unroll
                for (int qh = 0; qh < 2; ++qh) {
                    int qg = r0 + qh * 16 + lane15;
#pragma unroll
                    for (int r = 0; r < 4; ++r)
                        if (sbase + r > qg) st[qh][ct][r] = -3.0e38f;
                }
            }
        }

        // fixed-max softmax; per-lane l (q = lane15 fixed!)
#pragma unroll
        for (int qh = 0; qh < 2; ++qh)
#pragma unroll
            for (int ct = 0; ct < 4; ++ct)
#pragma unroll
                for (int r = 0; r < 4; ++r) {
                    float p = exp2f(st[qh][ct][r]);
                    st[qh][ct][r] = p;
                    l_acc[qh] += p;
                }

        // pack pairs of s-consecutive P and write b64; P stored [q][s]
#pragma unroll
        for (int qh = 0; qh < 2; ++qh) {
#pragma unroll
            for (int ct = 0; ct < 4; ++ct) {
                unsigned int w0 = pkbf(st[qh][ct][1], st[qh][ct][0]);
                unsigned int w1 = pkbf(st[qh][ct][3], st[qh][ct][2]);
                *(uint2*)&pw[(qh * 16 + lane15) * PSP + ct * 16 + quad * 4] =
                    make_uint2(w0, w1);
            }
        }

        // readback as A-fragments, PV
        bf16x8 pa[2][2];
#pragma unroll
        for (int qh = 0; qh < 2; ++qh) {
            pa[qh][0] = *(const bf16x8*)&pw[(qh * 16 + lane15) * PSP + quad * 8];
            pa[qh][1] = *(const bf16x8*)&pw[(qh * 16 + lane15) * PSP + 32 + quad * 8];
        }
#pragma unroll
        for (int kk = 0; kk < 2; ++kk)
#pragma unroll
            for (int hf = 0; hf < 4; ++hf) {
                o_acc[0][hf] = mfma16(pa[0][kk], vf[hf * 2 + kk], o_acc[0][hf]);
                o_acc[1][hf] = mfma16(pa[1][kk], vf[hf * 2 + kk], o_acc[1][hf]);
            }
    }

    // l: reduce across the 4 quads holding each q
#pragma unroll
    for (int qh = 0; qh < 2; ++qh) {
        float v = l_acc[qh];
        v += __shfl_xor(v, 16);
        v += __shfl_xor(v, 32);
        l_acc[qh] = v;
    }

    __syncthreads();  // Ps dead everywhere; smem becomes Ob

    // O partials (C layout: row=q offset, col=h) -> bf16 Ob
#pragma unroll
    for (int qh = 0; qh < 2; ++qh)
#pragma unroll
        for (int hf = 0; hf < 4; ++hf)
#pragma unroll
            for (int r = 0; r < 4; ++r)
                Ob[(wave * 32 + qh * 16 + quad * 4 + r) * 68 + hf * 16 + lane15] =
                    f2bf(o_acc[qh][hf][r]);
    if (quad == 0) {
        Ll[wave * 32 + lane15] = l_acc[0];
        Ll[wave * 32 + 16 + lane15] = l_acc[1];
    }
    __syncthreads();

    // merge: row = tid>>4 (32 q), 4 h per thread
    {
        int row = tid >> 4;
        int c4 = (tid & 15) * 4;
        float lsum = 0.f;
        f32x4 s4 = (f32x4){0.f, 0.f, 0.f, 0.f};
#pragma unroll
        for (int w = 0; w < 8; ++w) {
            lsum += Ll[w * 32 + row];
            uint2 d = *(const uint2*)&Ob[(w * 32 + row) * 68 + c4];
            s4[0] += __builtin_bit_cast(float, d.x << 16);
            s4[1] += __builtin_bit_cast(float, d.x & 0xffff0000u);
            s4[2] += __builtin_bit_cast(float, d.y << 16);
            s4[3] += __builtin_bit_cast(float, d.y & 0xffff0000u);
        }
        float inv = 1.0f / lsum;
        s4 *= inv;
        *(f32x4*)&out[((long)b * T_ + r0 + row) * H_ + c4] = s4;
    }
}

// ---------------------------------------------------------------------------
extern "C" void kernel_launch(void* const* d_in, const int* in_sizes, int n_in,
                              void* d_out, int out_size, void* d_ws, size_t ws_size,
                              hipStream_t stream) {
    const float* x  = (const float*)d_in[0];
    const float* Wk = (const float*)d_in[1];
    const float* Wq = (const float*)d_in[2];
    const float* Wv = (const float*)d_in[3];
    float* out = (float*)d_out;

    char* ws = (char*)d_ws;
    unsigned short* Kf  = (unsigned short*)(ws);               // 2 MB
    unsigned short* Qf  = (unsigned short*)(ws + (2u << 20));  // 2 MB
    unsigned short* Vf  = (unsigned short*)(ws + (4u << 20));  // 2 MB
    unsigned short* Wtp = (unsigned short*)(ws + (6u << 20));  // 192 KB

    wt_kernel<<<384, 256, 0, stream>>>(Wk, Wq, Wv, Wtp);
    proj_kernel<<<BT / 32, 256, 0, stream>>>(x, Wtp, Kf, Qf, Vf);
    attn_kernel<<<dim3(128, B_), 512, 0, stream>>>(Qf, Kf, Vf, out);
}

// Round 6
// 153.014 us; speedup vs baseline: 1.4502x; 1.4502x over previous
//
#include <hip/hip_runtime.h>

// B=4, T=4096, C=512, H=64 causal attention head, scale=C^-0.5, fp32 I/O.
// R6 = R5 with the launch-bounds spill fixed: __launch_bounds__(512,4).
// (R5's (512,8) capped unified VGPRs at 64 -> massive scratch spill:
//  FETCH 216MB/WRITE 289MB of spill traffic, attn 122us. VGPR@R4 was 60.)

typedef __attribute__((ext_vector_type(8))) __bf16 bf16x8;
typedef __attribute__((ext_vector_type(8))) unsigned short u16x8;
typedef __attribute__((ext_vector_type(4))) float f32x4;

#define B_ 4
#define T_ 4096
#define C_ 512
#define H_ 64
#define BT (B_ * T_)

#define QSCALE (0.04419417382415922f * 1.4426950408889634f)  // C^-0.5 * log2(e)

__device__ __forceinline__ unsigned short f2bf(float f) {
    unsigned int u = __builtin_bit_cast(unsigned int, f);
    u += 0x7fffu + ((u >> 16) & 1u);
    return (unsigned short)(u >> 16);
}

// pack hi16(b),hi16(a) -> u32 {bf16(lo) | bf16(hi)<<16}  (truncation)
__device__ __forceinline__ unsigned int pkbf(float hi, float lo) {
    return __builtin_amdgcn_perm(__builtin_bit_cast(unsigned int, hi),
                                 __builtin_bit_cast(unsigned int, lo), 0x07060302u);
}

__device__ __forceinline__ f32x4 mfma16(bf16x8 a, bf16x8 b, f32x4 c) {
    return __builtin_amdgcn_mfma_f32_16x16x32_bf16(a, b, c, 0, 0, 0);
}

// ---------------------------------------------------------------------------
// Kernel 0: Wt packed in MFMA B-fragment order.
// ---------------------------------------------------------------------------
__global__ __launch_bounds__(256) void wt_kernel(const float* __restrict__ Wk,
                                                 const float* __restrict__ Wq,
                                                 const float* __restrict__ Wv,
                                                 unsigned short* __restrict__ Wtp) {
    int gid = blockIdx.x * 256 + threadIdx.x;  // 3*64*512
    int fidx = gid >> 9;
    int li = gid & 511;
    int lane = li >> 3, j = li & 7;
    int m3 = fidx / 64;
    int rem = fidx & 63;
    int nt = rem >> 4, kc = rem & 15;
    int h = nt * 16 + (lane & 15);
    int c = kc * 32 + (lane >> 4) * 8 + j;
    const float* W = (m3 == 0) ? Wk : ((m3 == 1) ? Wq : Wv);
    Wtp[gid] = f2bf(W[c * H_ + h]);
}

// ---------------------------------------------------------------------------
// Kernel 1: projections. 32 rows/block, 256 thr = 2 strips x 2 kc-halves.
// ---------------------------------------------------------------------------
__global__ __launch_bounds__(256, 4) void proj_kernel(const float* __restrict__ x,
                                                      const unsigned short* __restrict__ Wtp,
                                                      unsigned short* __restrict__ Kf,
                                                      unsigned short* __restrict__ Qf,
                                                      unsigned short* __restrict__ Vf) {
    __shared__ __align__(16) char smem[2 * 64 * 52 * 4];   // 26624 B
    float* Mg = (float*)smem;                               // [2][64][52] f32
    unsigned short* Ks_l = (unsigned short*)smem;           // [32][68]
    unsigned short* Qs_l = Ks_l + 32 * 68;
    unsigned short* Vt_l = Qs_l + 32 * 68;                  // [64 h][34]

    const int tid = threadIdx.x;
    const int t0 = blockIdx.x * 32;
    const int wave = tid >> 6;
    const int ws = wave & 1;       // strip
    const int wh = wave >> 1;      // kc half
    const int lane = tid & 63;
    const int lane15 = lane & 15;
    const int quad = lane >> 4;

    f32x4 acc[12];
#pragma unroll
    for (int i = 0; i < 12; ++i) acc[i] = (f32x4){0.f, 0.f, 0.f, 0.f};

    const float* xrow = x + (long)(t0 + ws * 16 + lane15) * C_;

#pragma unroll
    for (int kk = 0; kk < 8; ++kk) {
        const int kc = wh * 8 + kk;
        const float4 a0 = *(const float4*)(xrow + kc * 32 + quad * 8);
        const float4 a1 = *(const float4*)(xrow + kc * 32 + quad * 8 + 4);
        u16x8 t;
        t[0] = f2bf(a0.x); t[1] = f2bf(a0.y); t[2] = f2bf(a0.z); t[3] = f2bf(a0.w);
        t[4] = f2bf(a1.x); t[5] = f2bf(a1.y); t[6] = f2bf(a1.z); t[7] = f2bf(a1.w);
        bf16x8 a = __builtin_bit_cast(bf16x8, t);
#pragma unroll
        for (int m3 = 0; m3 < 3; ++m3) {
#pragma unroll
            for (int nt = 0; nt < 4; ++nt) {
                const bf16x8 b = *(const bf16x8*)&Wtp[(((m3 * 4 + nt) * 16 + kc) << 9) + lane * 8];
                acc[m3 * 4 + nt] = mfma16(a, b, acc[m3 * 4 + nt]);
            }
        }
    }

    // kc merge through LDS
    if (wh == 1) {
        float* mg = Mg + (ws * 64 + lane) * 52;
#pragma unroll
        for (int i = 0; i < 12; ++i) *(f32x4*)(mg + i * 4) = acc[i];
    }
    __syncthreads();
    if (wh == 0) {
        const float* mg = Mg + (ws * 64 + lane) * 52;
#pragma unroll
        for (int i = 0; i < 12; ++i) acc[i] += *(const f32x4*)(mg + i * 4);
    }
    __syncthreads();  // Mg dead

    if (wh == 0) {
#pragma unroll
        for (int nt = 0; nt < 4; ++nt) {
            int col = nt * 16 + lane15;
#pragma unroll
            for (int r = 0; r < 4; ++r) {
                int row_l = ws * 16 + quad * 4 + r;
                Ks_l[row_l * 68 + col] = f2bf(acc[0 * 4 + nt][r]);
                Qs_l[row_l * 68 + col] = f2bf(acc[1 * 4 + nt][r] * QSCALE);
                Vt_l[col * 34 + row_l] = f2bf(acc[2 * 4 + nt][r]);
            }
        }
    }
    __syncthreads();

    // Packed writes: 12 frags, 3 per wave.
    const int b = t0 >> 12;
    const int tloc = t0 & 4095;
    const int st = wave >> 1, kk = wave & 1;
    const long gs = (long)(b * 256 + (tloc >> 4) + st);
    bf16x8 kv = *(const bf16x8*)&Ks_l[(st * 16 + lane15) * 68 + kk * 32 + quad * 8];
    *(bf16x8*)&Kf[(gs * 2 + kk) * 512 + lane * 8] = kv;
    bf16x8 qv = *(const bf16x8*)&Qs_l[(st * 16 + lane15) * 68 + kk * 32 + quad * 8];
    *(bf16x8*)&Qf[(gs * 2 + kk) * 512 + lane * 8] = qv;
    // Vf: block covers s_local64 = (tloc&32) + [0,32); frag f = hf*2 + vkk
    const int hf = wave;                      // 0..3
    const int vkk = (tloc >> 5) & 1;
    bf16x8 vv = *(const bf16x8*)&Vt_l[(hf * 16 + lane15) * 34 + quad * 8];
    const long sb = (long)(b * 64 + (tloc >> 6));
    *(bf16x8*)&Vf[(sb * 8 + hf * 2 + vkk) * 512 + lane * 8] = vv;
}

// ---------------------------------------------------------------------------
// Kernel 2: attention. Block = (b, 32-row strip), 8-way K-split waves.
// S^T = K*Q^T so P regs are s-contiguous -> perm-pack + ds_write_b64.
// ---------------------------------------------------------------------------
#define PSP 72
#define SMEM_A (8 * 32 * PSP * 2 + 8 * 32 * 4)

__global__ __launch_bounds__(512, 4) void attn_kernel(const unsigned short* __restrict__ Qf,
                                                      const unsigned short* __restrict__ Kf,
                                                      const unsigned short* __restrict__ Vf,
                                                      float* __restrict__ out) {
    __shared__ __align__(16) char smem[SMEM_A];
    unsigned short* Ps = (unsigned short*)smem;          // loop phase (per-wave)
    unsigned short* Ob = (unsigned short*)smem;          // merge phase, bf16 pitch 68
    float* Ll = (float*)(smem + 8 * 32 * PSP * 2);

    const int tid = threadIdx.x;
    const int wave = tid >> 6;
    const int lane = tid & 63;
    const int lane15 = lane & 15;
    const int quad = lane >> 4;
    const int b = blockIdx.y;
    // complementary pairing: y<2 descending, y>=2 ascending
    const int strip32 = (blockIdx.y < 2) ? (127 - blockIdx.x) : blockIdx.x;
    const int r0 = strip32 * 32;

    // Q as B-operand fragments (B layout == stored frag layout)
    const unsigned short* qb = Qf + ((long)(b * 256 + strip32 * 2) * 2) * 512 + lane * 8;
    bf16x8 qf[2][2];
    qf[0][0] = *(const bf16x8*)qb;
    qf[0][1] = *(const bf16x8*)(qb + 512);
    qf[1][0] = *(const bf16x8*)(qb + 1024);
    qf[1][1] = *(const bf16x8*)(qb + 1536);

    f32x4 o_acc[2][4];
    float l_acc[2] = {0.f, 0.f};
#pragma unroll
    for (int qh = 0; qh < 2; ++qh)
#pragma unroll
        for (int hf = 0; hf < 4; ++hf) o_acc[qh][hf] = (f32x4){0.f, 0.f, 0.f, 0.f};

    const int ntiles = (r0 + 95) >> 6;
    unsigned short* pw = Ps + wave * 32 * PSP;

    for (int kc = wave; kc < ntiles; kc += 8) {
        const int s0 = kc * 64;
        const unsigned short* kb = Kf + ((long)(b * 256 + (s0 >> 4)) * 2) * 512 + lane * 8;
        const unsigned short* vb = Vf + ((long)(b * 64 + (s0 >> 6)) * 8) * 512 + lane * 8;

        // S^T = K Q^T : element (s = s0+ct*16+quad*4+r, q = r0+qh*16+lane15)
        f32x4 st[2][4];
#pragma unroll
        for (int ct = 0; ct < 4; ++ct) {
            bf16x8 k0 = *(const bf16x8*)(kb + ct * 1024);
            bf16x8 k1 = *(const bf16x8*)(kb + ct * 1024 + 512);
#pragma unroll
            for (int qh = 0; qh < 2; ++qh) {
                f32x4 z = (f32x4){0.f, 0.f, 0.f, 0.f};
                z = mfma16(k0, qf[qh][0], z);
                z = mfma16(k1, qf[qh][1], z);
                st[qh][ct] = z;
            }
        }

        // V^T fragments (overlap with softmax)
        bf16x8 vf[8];
#pragma unroll
        for (int f = 0; f < 8; ++f) vf[f] = *(const bf16x8*)(vb + f * 512);

        // causal mask on straddle tiles
        if (s0 + 63 > r0) {
#pragma unroll
            for (int ct = 0; ct < 4; ++ct) {
                int sbase = s0 + ct * 16 + quad * 4;
#pragma unroll
                for (int qh = 0; qh < 2; ++qh) {
                    int qg = r0 + qh * 16 + lane15;
#pragma unroll
                    for (int r = 0; r < 4; ++r)
                        if (sbase + r > qg) st[qh][ct][r] = -3.0e38f;
                }
            }
        }

        // fixed-max softmax; per-lane l (q = lane15 fixed!)
#pragma unroll
        for (int qh = 0; qh < 2; ++qh)
#pragma unroll
            for (int ct = 0; ct < 4; ++ct)
#pragma unroll
                for (int r = 0; r < 4; ++r) {
                    float p = exp2f(st[qh][ct][r]);
                    st[qh][ct][r] = p;
                    l_acc[qh] += p;
                }

        // pack pairs of s-consecutive P and write b64; P stored [q][s]
#pragma unroll
        for (int qh = 0; qh < 2; ++qh) {
#pragma unroll
            for (int ct = 0; ct < 4; ++ct) {
                unsigned int w0 = pkbf(st[qh][ct][1], st[qh][ct][0]);
                unsigned int w1 = pkbf(st[qh][ct][3], st[qh][ct][2]);
                *(uint2*)&pw[(qh * 16 + lane15) * PSP + ct * 16 + quad * 4] =
                    make_uint2(w0, w1);
            }
        }

        // readback as A-fragments, PV
        bf16x8 pa[2][2];
#pragma unroll
        for (int qh = 0; qh < 2; ++qh) {
            pa[qh][0] = *(const bf16x8*)&pw[(qh * 16 + lane15) * PSP + quad * 8];
            pa[qh][1] = *(const bf16x8*)&pw[(qh * 16 + lane15) * PSP + 32 + quad * 8];
        }
#pragma unroll
        for (int kk = 0; kk < 2; ++kk)
#pragma unroll
            for (int hf = 0; hf < 4; ++hf) {
                o_acc[0][hf] = mfma16(pa[0][kk], vf[hf * 2 + kk], o_acc[0][hf]);
                o_acc[1][hf] = mfma16(pa[1][kk], vf[hf * 2 + kk], o_acc[1][hf]);
            }
    }

    // l: reduce across the 4 quads holding each q
#pragma unroll
    for (int qh = 0; qh < 2; ++qh) {
        float v = l_acc[qh];
        v += __shfl_xor(v, 16);
        v += __shfl_xor(v, 32);
        l_acc[qh] = v;
    }

    __syncthreads();  // Ps dead everywhere; smem becomes Ob

    // O partials (C layout: row=q offset, col=h) -> bf16 Ob
#pragma unroll
    for (int qh = 0; qh < 2; ++qh)
#pragma unroll
        for (int hf = 0; hf < 4; ++hf)
#pragma unroll
            for (int r = 0; r < 4; ++r)
                Ob[(wave * 32 + qh * 16 + quad * 4 + r) * 68 + hf * 16 + lane15] =
                    f2bf(o_acc[qh][hf][r]);
    if (quad == 0) {
        Ll[wave * 32 + lane15] = l_acc[0];
        Ll[wave * 32 + 16 + lane15] = l_acc[1];
    }
    __syncthreads();

    // merge: row = tid>>4 (32 q), 4 h per thread
    {
        int row = tid >> 4;
        int c4 = (tid & 15) * 4;
        float lsum = 0.f;
        f32x4 s4 = (f32x4){0.f, 0.f, 0.f, 0.f};
#pragma unroll
        for (int w = 0; w < 8; ++w) {
            lsum += Ll[w * 32 + row];
            uint2 d = *(const uint2*)&Ob[(w * 32 + row) * 68 + c4];
            s4[0] += __builtin_bit_cast(float, d.x << 16);
            s4[1] += __builtin_bit_cast(float, d.x & 0xffff0000u);
            s4[2] += __builtin_bit_cast(float, d.y << 16);
            s4[3] += __builtin_bit_cast(float, d.y & 0xffff0000u);
        }
        float inv = 1.0f / lsum;
        s4 *= inv;
        *(f32x4*)&out[((long)b * T_ + r0 + row) * H_ + c4] = s4;
    }
}

// ---------------------------------------------------------------------------
extern "C" void kernel_launch(void* const* d_in, const int* in_sizes, int n_in,
                              void* d_out, int out_size, void* d_ws, size_t ws_size,
                              hipStream_t stream) {
    const float* x  = (const float*)d_in[0];
    const float* Wk = (const float*)d_in[1];
    const float* Wq = (const float*)d_in[2];
    const float* Wv = (const float*)d_in[3];
    float* out = (float*)d_out;

    char* ws = (char*)d_ws;
    unsigned short* Kf  = (unsigned short*)(ws);               // 2 MB
    unsigned short* Qf  = (unsigned short*)(ws + (2u << 20));  // 2 MB
    unsigned short* Vf  = (unsigned short*)(ws + (4u << 20));  // 2 MB
    unsigned short* Wtp = (unsigned short*)(ws + (6u << 20));  // 192 KB

    wt_kernel<<<384, 256, 0, stream>>>(Wk, Wq, Wv, Wtp);
    proj_kernel<<<BT / 32, 256, 0, stream>>>(x, Wtp, Kf, Qf, Vf);
    attn_kernel<<<dim3(128, B_), 512, 0, stream>>>(Qf, Kf, Vf, out);
}

// Round 7
// 120.279 us; speedup vs baseline: 1.8449x; 1.2722x over previous
//
#include <hip/hip_runtime.h>

// B=4, T=4096, C=512, H=64 causal attention head, scale=C^-0.5, fp32 I/O.
// R7: attn = uniform chunked blocks (b, 64-row Q tile, <=16 K-tile chunk),
// 4 waves split Q, shared K/V tile, register-pipelined global frag loads,
// partial (O,l) to ws + merge kernel. proj = 1024 blocks, 4-way kc split.

typedef __attribute__((ext_vector_type(8))) __bf16 bf16x8;
typedef __attribute__((ext_vector_type(8))) unsigned short u16x8;
typedef __attribute__((ext_vector_type(4))) float f32x4;

#define B_ 4
#define T_ 4096
#define C_ 512
#define H_ 64
#define BT (B_ * T_)

#define QSCALE (0.04419417382415922f * 1.4426950408889634f)  // C^-0.5 * log2(e)

__device__ __forceinline__ unsigned short f2bf(float f) {
    unsigned int u = __builtin_bit_cast(unsigned int, f);
    u += 0x7fffu + ((u >> 16) & 1u);
    return (unsigned short)(u >> 16);
}

__device__ __forceinline__ unsigned int pkbf(float hi, float lo) {
    return __builtin_amdgcn_perm(__builtin_bit_cast(unsigned int, hi),
                                 __builtin_bit_cast(unsigned int, lo), 0x07060302u);
}

__device__ __forceinline__ f32x4 mfma16(bf16x8 a, bf16x8 b, f32x4 c) {
    return __builtin_amdgcn_mfma_f32_16x16x32_bf16(a, b, c, 0, 0, 0);
}

// ---------------------------------------------------------------------------
// Kernel 0: Wt packed in MFMA B-fragment order.
// ---------------------------------------------------------------------------
__global__ __launch_bounds__(256) void wt_kernel(const float* __restrict__ Wk,
                                                 const float* __restrict__ Wq,
                                                 const float* __restrict__ Wv,
                                                 unsigned short* __restrict__ Wtp) {
    int gid = blockIdx.x * 256 + threadIdx.x;  // 3*64*512
    int fidx = gid >> 9;
    int li = gid & 511;
    int lane = li >> 3, j = li & 7;
    int m3 = fidx / 64;
    int rem = fidx & 63;
    int nt = rem >> 4, kc = rem & 15;
    int h = nt * 16 + (lane & 15);
    int c = kc * 32 + (lane >> 4) * 8 + j;
    const float* W = (m3 == 0) ? Wk : ((m3 == 1) ? Wq : Wv);
    Wtp[gid] = f2bf(W[c * H_ + h]);
}

// ---------------------------------------------------------------------------
// Kernel 1: projections. 16 rows/block, 256 thr = 4 kc-quarters, LDS merge.
// ---------------------------------------------------------------------------
__global__ __launch_bounds__(256, 4) void proj_kernel(const float* __restrict__ x,
                                                      const unsigned short* __restrict__ Wtp,
                                                      unsigned short* __restrict__ Kf,
                                                      unsigned short* __restrict__ Qf,
                                                      unsigned short* __restrict__ Vf) {
    __shared__ __align__(16) char smem[3 * 64 * 52 * 4];  // 39936 B
    float* Mg = (float*)smem;                              // [3][64][52] f32
    unsigned short* Ks_l = (unsigned short*)smem;          // [16][68]
    unsigned short* Qs_l = Ks_l + 16 * 68;                 // [16][68]
    unsigned short* Vt_l = Qs_l + 16 * 68;                 // [64 h][18]

    const int tid = threadIdx.x;
    const int t0 = blockIdx.x * 16;
    const int wave = tid >> 6;     // kc quarter
    const int lane = tid & 63;
    const int lane15 = lane & 15;
    const int quad = lane >> 4;

    f32x4 acc[12];
#pragma unroll
    for (int i = 0; i < 12; ++i) acc[i] = (f32x4){0.f, 0.f, 0.f, 0.f};

    const float* xrow = x + (long)(t0 + lane15) * C_;

#pragma unroll
    for (int kk = 0; kk < 4; ++kk) {
        const int kc = wave * 4 + kk;
        const float4 a0 = *(const float4*)(xrow + kc * 32 + quad * 8);
        const float4 a1 = *(const float4*)(xrow + kc * 32 + quad * 8 + 4);
        u16x8 t;
        t[0] = f2bf(a0.x); t[1] = f2bf(a0.y); t[2] = f2bf(a0.z); t[3] = f2bf(a0.w);
        t[4] = f2bf(a1.x); t[5] = f2bf(a1.y); t[6] = f2bf(a1.z); t[7] = f2bf(a1.w);
        bf16x8 a = __builtin_bit_cast(bf16x8, t);
#pragma unroll
        for (int m3 = 0; m3 < 3; ++m3) {
#pragma unroll
            for (int nt = 0; nt < 4; ++nt) {
                const bf16x8 b = *(const bf16x8*)&Wtp[(((m3 * 4 + nt) * 16 + kc) << 9) + lane * 8];
                acc[m3 * 4 + nt] = mfma16(a, b, acc[m3 * 4 + nt]);
            }
        }
    }

    // 4-way kc merge: waves 1..3 produce, wave 0 accumulates.
    if (wave > 0) {
        float* mg = Mg + ((wave - 1) * 64 + lane) * 52;
#pragma unroll
        for (int i = 0; i < 12; ++i) *(f32x4*)(mg + i * 4) = acc[i];
    }
    __syncthreads();
    if (wave == 0) {
#pragma unroll
        for (int w = 0; w < 3; ++w) {
            const float* mg = Mg + (w * 64 + lane) * 52;
#pragma unroll
            for (int i = 0; i < 12; ++i) acc[i] += *(const f32x4*)(mg + i * 4);
        }
    }
    __syncthreads();  // Mg dead

    if (wave == 0) {
#pragma unroll
        for (int nt = 0; nt < 4; ++nt) {
            int col = nt * 16 + lane15;
#pragma unroll
            for (int r = 0; r < 4; ++r) {
                int row_l = quad * 4 + r;   // C layout
                Ks_l[row_l * 68 + col] = f2bf(acc[0 * 4 + nt][r]);
                Qs_l[row_l * 68 + col] = f2bf(acc[1 * 4 + nt][r] * QSCALE);
                Vt_l[col * 18 + row_l] = f2bf(acc[2 * 4 + nt][r]);
            }
        }
    }
    __syncthreads();

    const int b = t0 >> 12;
    const int tloc = t0 & 4095;
    const long gs = (long)(b * 256 + (tloc >> 4));

    // K/Q packed writes: wave0=K.kk0, wave1=K.kk1, wave2=Q.kk0, wave3=Q.kk1
    {
        const unsigned short* src = (wave < 2) ? Ks_l : Qs_l;
        unsigned short* dst = (wave < 2) ? Kf : Qf;
        const int kk = wave & 1;
        bf16x8 v = *(const bf16x8*)&src[lane15 * 68 + kk * 32 + quad * 8];
        *(bf16x8*)&dst[(gs * 2 + kk) * 512 + lane * 8] = v;
    }
    // Vf: this block covers 16 rows at position tl16 within its 64-row block.
    {
        const int tl16 = (tloc >> 4) & 3;
        const int kkv = tl16 >> 1;
        if ((quad >> 1) == (tl16 & 1)) {
            bf16x8 v = *(const bf16x8*)&Vt_l[(wave * 16 + lane15) * 18 + (quad & 1) * 8];
            const long sb = (long)(b * 64 + (tloc >> 6));
            *(bf16x8*)&Vf[(sb * 8 + wave * 2 + kkv) * 512 + lane * 8] = v;
        }
    }
}

// ---------------------------------------------------------------------------
// Kernel 2: attention partials. Block = (b, 64-row Q tile qt, chunk of <=16
// K tiles). 4 waves split Q 16 rows each, share K/V tiles, pipeline loads.
// ---------------------------------------------------------------------------
#define PSP 72

__global__ __launch_bounds__(256, 4) void attn_kernel(const unsigned short* __restrict__ Qf,
                                                      const unsigned short* __restrict__ Kf,
                                                      const unsigned short* __restrict__ Vf,
                                                      float* __restrict__ Op,
                                                      float* __restrict__ lp) {
    __shared__ __align__(16) unsigned short Ps[4 * 16 * PSP];  // 9216 B

    const int tid = threadIdx.x;
    const int wave = tid >> 6;
    const int lane = tid & 63;
    const int lane15 = lane & 15;
    const int quad = lane >> 4;
    const int b = blockIdx.y;

    // z -> (qt, chunk): group g has qt in [16g,16g+16), g+1 chunks each.
    const int z = blockIdx.x;  // 0..159
    int g, zb;
    if (z < 16)      { g = 0; zb = 0; }
    else if (z < 48) { g = 1; zb = 16; }
    else if (z < 96) { g = 2; zb = 48; }
    else             { g = 3; zb = 96; }
    const int idx = z - zb;
    const int qt = g * 16 + idx / (g + 1);
    const int chunk = idx % (g + 1);
    const int ntt = min(16, qt + 1 - chunk * 16);  // tiles in this chunk
    const int t0k = chunk * 16;

    // Q fragments: wave owns rows qt*64 + wave*16 .. +16
    const long gs_q = (long)(b * 256 + qt * 4 + wave);
    const unsigned short* qb = Qf + gs_q * 1024 + lane * 8;
    const bf16x8 qf0 = *(const bf16x8*)qb;
    const bf16x8 qf1 = *(const bf16x8*)(qb + 512);

    f32x4 o_acc[4];
    float l_acc = 0.f;
#pragma unroll
    for (int hf = 0; hf < 4; ++hf) o_acc[hf] = (f32x4){0.f, 0.f, 0.f, 0.f};

    unsigned short* pw = Ps + wave * 16 * PSP;

    // preload tile 0
    bf16x8 kf[8], vf[8];
    {
        const int kc = t0k;
        const unsigned short* kb = Kf + (long)(b * 256 + kc * 4) * 1024 + lane * 8;
        const unsigned short* vb = Vf + (long)(b * 64 + kc) * 4096 + lane * 8;
#pragma unroll
        for (int ct = 0; ct < 4; ++ct) {
            kf[ct * 2 + 0] = *(const bf16x8*)(kb + ct * 1024);
            kf[ct * 2 + 1] = *(const bf16x8*)(kb + ct * 1024 + 512);
        }
#pragma unroll
        for (int f = 0; f < 8; ++f) vf[f] = *(const bf16x8*)(vb + f * 512);
    }

    for (int t = 0; t < ntt; ++t) {
        const int kc = t0k + t;
        const int tn = (t + 1 < ntt) ? (t + 1) : t;   // clamped prefetch
        const int kcn = t0k + tn;
        const unsigned short* kbn = Kf + (long)(b * 256 + kcn * 4) * 1024 + lane * 8;
        const unsigned short* vbn = Vf + (long)(b * 64 + kcn) * 4096 + lane * 8;

        // S^T = K Q^T : (s = kc*64 + ct*16 + quad*4 + r, q = lane15)
        f32x4 st[4];
#pragma unroll
        for (int ct = 0; ct < 4; ++ct) {
            f32x4 zz = (f32x4){0.f, 0.f, 0.f, 0.f};
            zz = mfma16(kf[ct * 2 + 0], qf0, zz);
            zz = mfma16(kf[ct * 2 + 1], qf1, zz);
            st[ct] = zz;
        }

        // prefetch next K (kf regs free after the MFMAs above consumed them)
#pragma unroll
        for (int ct = 0; ct < 4; ++ct) {
            kf[ct * 2 + 0] = *(const bf16x8*)(kbn + ct * 1024);
            kf[ct * 2 + 1] = *(const bf16x8*)(kbn + ct * 1024 + 512);
        }

        // causal mask only on the diagonal tile
        if (kc == qt) {
            const int qg = wave * 16 + lane15;
#pragma unroll
            for (int ct = 0; ct < 4; ++ct) {
                const int sb = ct * 16 + quad * 4;
#pragma unroll
                for (int r = 0; r < 4; ++r)
                    if (sb + r > qg) st[ct][r] = -3.0e38f;
            }
        }

        // fixed-max softmax (scores bounded; exp2 domain), per-lane l (q fixed)
#pragma unroll
        for (int ct = 0; ct < 4; ++ct)
#pragma unroll
            for (int r = 0; r < 4; ++r) {
                float p = __builtin_amdgcn_exp2f(st[ct][r]);
                st[ct][r] = p;
                l_acc += p;
            }

        // pack P (s-contiguous in regs) -> LDS [q][s]
#pragma unroll
        for (int ct = 0; ct < 4; ++ct) {
            unsigned int w0 = pkbf(st[ct][1], st[ct][0]);
            unsigned int w1 = pkbf(st[ct][3], st[ct][2]);
            *(uint2*)&pw[lane15 * PSP + ct * 16 + quad * 4] = make_uint2(w0, w1);
        }

        // readback as A fragments, PV
        bf16x8 pa0 = *(const bf16x8*)&pw[lane15 * PSP + quad * 8];
        bf16x8 pa1 = *(const bf16x8*)&pw[lane15 * PSP + 32 + quad * 8];
#pragma unroll
        for (int hf = 0; hf < 4; ++hf) {
            o_acc[hf] = mfma16(pa0, vf[hf * 2 + 0], o_acc[hf]);
            o_acc[hf] = mfma16(pa1, vf[hf * 2 + 1], o_acc[hf]);
        }

        // prefetch next V
#pragma unroll
        for (int f = 0; f < 8; ++f) vf[f] = *(const bf16x8*)(vbn + f * 512);
    }

    // l: sum over the 4 quads holding each q
    l_acc += __shfl_xor(l_acc, 16);
    l_acc += __shfl_xor(l_acc, 32);

    // write partials
    const long pbase = ((long)(b * 64 + qt) * 4 + chunk) * 64;
    if (quad == 0) lp[pbase + wave * 16 + lane15] = l_acc;
    float* op = Op + (pbase + wave * 16) * 64;
#pragma unroll
    for (int hf = 0; hf < 4; ++hf)
#pragma unroll
        for (int r = 0; r < 4; ++r)
            op[(quad * 4 + r) * 64 + hf * 16 + lane15] = o_acc[hf][r];
}

// ---------------------------------------------------------------------------
// Kernel 3: merge chunk partials. Block = (qt, b), 256 threads.
// ---------------------------------------------------------------------------
__global__ __launch_bounds__(256) void merge_kernel(const float* __restrict__ Op,
                                                    const float* __restrict__ lp,
                                                    float* __restrict__ out) {
    const int qt = blockIdx.x;
    const int b = blockIdx.y;
    const int nc = 1 + (qt >> 4);   // ceil((qt+1)/16)
    const int tid = threadIdx.x;
    const int row = tid >> 2;
    const int seg = (tid & 3) << 4;

    const long base = (long)(b * 64 + qt) * 4;
    float l = 0.f;
    f32x4 a[4];
#pragma unroll
    for (int j = 0; j < 4; ++j) a[j] = (f32x4){0.f, 0.f, 0.f, 0.f};

    for (int c = 0; c < nc; ++c) {
        l += lp[(base + c) * 64 + row];
        const float* op = Op + ((base + c) * 64 + row) * 64 + seg;
#pragma unroll
        for (int j = 0; j < 4; ++j) a[j] += *(const f32x4*)(op + j * 4);
    }
    const float inv = 1.0f / l;
    float* o = out + ((long)b * T_ + qt * 64 + row) * H_ + seg;
#pragma unroll
    for (int j = 0; j < 4; ++j) *(f32x4*)(o + j * 4) = a[j] * inv;
}

// ---------------------------------------------------------------------------
extern "C" void kernel_launch(void* const* d_in, const int* in_sizes, int n_in,
                              void* d_out, int out_size, void* d_ws, size_t ws_size,
                              hipStream_t stream) {
    const float* x  = (const float*)d_in[0];
    const float* Wk = (const float*)d_in[1];
    const float* Wq = (const float*)d_in[2];
    const float* Wv = (const float*)d_in[3];
    float* out = (float*)d_out;

    char* ws = (char*)d_ws;
    unsigned short* Kf  = (unsigned short*)(ws);                // 2 MB
    unsigned short* Qf  = (unsigned short*)(ws + (2u << 20));   // 2 MB
    unsigned short* Vf  = (unsigned short*)(ws + (4u << 20));   // 2 MB
    unsigned short* Wtp = (unsigned short*)(ws + (6u << 20));   // 192 KB
    float* Op = (float*)(ws + (8u << 20));                      // 16 MB
    float* lp = (float*)(ws + (24u << 20));                     // 256 KB

    wt_kernel<<<384, 256, 0, stream>>>(Wk, Wq, Wv, Wtp);
    proj_kernel<<<BT / 16, 256, 0, stream>>>(x, Wtp, Kf, Qf, Vf);
    attn_kernel<<<dim3(160, B_), 256, 0, stream>>>(Qf, Kf, Vf, Op, lp);
    merge_kernel<<<dim3(64, B_), 256, 0, stream>>>(Op, lp, out);
}